// Round 2
// baseline (173.429 us; speedup 1.0000x reference)
//
#include <hip/hip_runtime.h>

#define Bsz 256
#define Dd  4096
#define MAXR 15
#define FMAX 3.402823466e+38f
#define BK 64
#define LSTRIDE 72              // 9 granules (odd): conflict-free phases, 16B-aligned rows

typedef short bf16x8 __attribute__((ext_vector_type(8)));
typedef float f32x4  __attribute__((ext_vector_type(4)));

__device__ __forceinline__ unsigned short f2bf(float f) {
    unsigned int u = __float_as_uint(f);
    unsigned int r = (u + 0x7fffu + ((u >> 16) & 1u)) >> 16;   // RNE
    return (unsigned short)r;
}
__device__ __forceinline__ float bf2f(unsigned short h) {
    return __uint_as_float(((unsigned int)h) << 16);
}

// ---- Kernel 1 (tiny): x fp32 -> bf16 (same rounding as champion's fused conversion) ----
__global__ __launch_bounds__(256) void k_xconv(const float* __restrict__ x,
                                               unsigned short* __restrict__ xb) {
    const int b = blockIdx.x;
    const int tid = threadIdx.x;
    const float* xp = x + (size_t)b * Dd;
    unsigned short* xo = xb + (size_t)b * Dd;
    #pragma unroll
    for (int c = 0; c < 4; ++c) {
        int e = c * 1024 + tid * 4;
        float4 v = *(const float4*)(xp + e);
        unsigned short o4[4] = { f2bf(v.x), f2bf(v.y), f2bf(v.z), f2bf(v.w) };
        *(uint2*)(xo + e) = *(const uint2*)o4;
    }
}

// ---- Kernel 2 (v3, fused): part[z] = X @ S(K-chunk z), S = 0.5(W+W^T) built on the fly ----
// BM=256 x BN=64, 512 threads / 8 waves (4m x 2n). Per BK step:
//   A: write T1[k][n] = W[kbase+k0+k][n0+n] (fp32, coalesced rows; padded [64][66])
//   B: convert s = 0.5(W[n][k] (regs) + T1[k][n] (transposed read)) -> f2bf hi/lo -> Bh/Bl
//   C: MFMA; A-fragments read DIRECTLY from xb (L2-resident) -> no As staging, LDS = 35.3 KB
// S values, MFMA order, part layout bit-identical to the shi/slo champion -> absmax 0.0.
__global__ __launch_bounds__(512, 2) void k_gemm(const unsigned short* __restrict__ xb,
                                              const float* __restrict__ W,
                                              float* __restrict__ part,
                                              int kchunk) {
    __shared__ __align__(16) unsigned short Bh[64 * LSTRIDE];    //  9 KB
    __shared__ __align__(16) unsigned short Bl[64 * LSTRIDE];    //  9 KB
    __shared__ __align__(8)  float T1[64 * 66];                  // 16.9 KB (pad 66: 2-4 way max)
    const int tid = threadIdx.x;
    const int n0 = blockIdx.x * 64;
    const int kbase = blockIdx.z * kchunk;
    const int w = tid >> 6, lane = tid & 63;
    const int ln = lane & 15, quad = lane >> 4;
    const int wm = w >> 1, wn = w & 1;     // wave grid: 4 in M, 2 in N

    // staging/convert slot: 64 rows x 8 granules-of-8
    const int rT = tid >> 3;               // 0..63
    const int cT8 = (tid & 7) * 8;         // 0..56
    const float* w1p = W + (size_t)(kbase + rT) * Dd + (n0 + cT8);   // k-panel row (advance k0*Dd)
    const float* w2p = W + (size_t)(n0 + rT) * Dd + (kbase + cT8);   // n-panel row (advance k0)

    // per-thread A-fragment row bases (direct-from-xb A operand)
    const unsigned short* xA[4];
    #pragma unroll
    for (int mt = 0; mt < 4; ++mt)
        xA[mt] = xb + (size_t)(wm * 64 + mt * 16 + ln) * Dd + kbase;

    f32x4 acc[4][2];
    #pragma unroll
    for (int mt = 0; mt < 4; ++mt)
        #pragma unroll
        for (int ct = 0; ct < 2; ++ct)
            #pragma unroll
            for (int rr = 0; rr < 4; ++rr) acc[mt][ct][rr] = 0.0f;

    // prologue: current-step W panels in registers
    float4 w1a = *(const float4*)(w1p);
    float4 w1b = *(const float4*)(w1p + 4);
    float4 w2a = *(const float4*)(w2p);
    float4 w2b = *(const float4*)(w2p + 4);

    for (int k0 = 0; k0 < kchunk; k0 += BK) {
        __syncthreads();                                   // A: T1 free (prev convert done)
        {   // stage k-panel tile into T1 (float2 writes, 8B-aligned rows of 264B)
            float2 p0 = { w1a.x, w1a.y }, p1 = { w1a.z, w1a.w };
            float2 p2 = { w1b.x, w1b.y }, p3 = { w1b.z, w1b.w };
            float* t = &T1[rT * 66 + cT8];
            *(float2*)(t + 0) = p0; *(float2*)(t + 2) = p1;
            *(float2*)(t + 4) = p2; *(float2*)(t + 6) = p3;
        }
        // prefetch next step's W panels (in flight across convert+MFMA phases)
        int kn = k0 + BK;
        int ks = (kn < kchunk) ? kn : 0;
        float4 nw1a = *(const float4*)(w1p + (size_t)ks * Dd);
        float4 nw1b = *(const float4*)(w1p + (size_t)ks * Dd + 4);
        float4 nw2a = *(const float4*)(w2p + ks);
        float4 nw2b = *(const float4*)(w2p + ks + 4);
        __syncthreads();                                   // B: T1 visible
        {   // convert: s[k][n] for this thread's (n=rT, k in [cT8, cT8+8))
            const float* w2f = (const float*)&w2a;         // w2a/w2b contiguous in j
            float sv[8];
            #pragma unroll
            for (int j = 0; j < 4; ++j)
                sv[j] = 0.5f * (w2f[j] + T1[(cT8 + j) * 66 + rT]);
            const float* w2g = (const float*)&w2b;
            #pragma unroll
            for (int j = 0; j < 4; ++j)
                sv[4 + j] = 0.5f * (w2g[j] + T1[(cT8 + 4 + j) * 66 + rT]);
            unsigned short vh[8], vl[8];
            #pragma unroll
            for (int j = 0; j < 8; ++j) {
                vh[j] = f2bf(sv[j]);
                vl[j] = f2bf(sv[j] - bf2f(vh[j]));
            }
            *(bf16x8*)&Bh[rT * LSTRIDE + cT8] = *(const bf16x8*)&vh[0];
            *(bf16x8*)&Bl[rT * LSTRIDE + cT8] = *(const bf16x8*)&vl[0];
        }
        __syncthreads();                                   // C: Bh/Bl visible
        #pragma unroll
        for (int kk = 0; kk < BK; kk += 32) {
            const int gr = (kk >> 3) + quad;
            bf16x8 a[4];
            #pragma unroll
            for (int mt = 0; mt < 4; ++mt)
                a[mt] = *(const bf16x8*)(xA[mt] + k0 + gr * 8);   // L2-resident xb
            #pragma unroll
            for (int ct = 0; ct < 2; ++ct) {
                int rb = wn * 32 + ct * 16 + ln;
                bf16x8 bh = *(const bf16x8*)&Bh[rb * LSTRIDE + gr * 8];
                bf16x8 bl = *(const bf16x8*)&Bl[rb * LSTRIDE + gr * 8];
                #pragma unroll
                for (int mt = 0; mt < 4; ++mt) {
                    acc[mt][ct] = __builtin_amdgcn_mfma_f32_16x16x32_bf16(a[mt], bh, acc[mt][ct], 0, 0, 0);
                    acc[mt][ct] = __builtin_amdgcn_mfma_f32_16x16x32_bf16(a[mt], bl, acc[mt][ct], 0, 0, 0);
                }
            }
        }
        w1a = nw1a; w1b = nw1b; w2a = nw2a; w2b = nw2b;    // rotate prefetch
    }
    float* prow = part + (size_t)blockIdx.z * (Bsz * Dd);
    #pragma unroll
    for (int mt = 0; mt < 4; ++mt)
        #pragma unroll
        for (int ct = 0; ct < 2; ++ct)
            #pragma unroll
            for (int rr = 0; rr < 4; ++rr) {
                int m = wm * 64 + mt * 16 + quad * 4 + rr;
                int n = n0 + wn * 32 + ct * 16 + ln;
                prow[(size_t)m * Dd + n] = acc[mt][ct][rr];
            }
}

// ---------------- block reduction helpers (256 threads = 4 waves) ----------------
__device__ __forceinline__ float block_max256(float v, float* redf) {
    #pragma unroll
    for (int off = 32; off; off >>= 1) v = fmaxf(v, __shfl_down(v, off));
    __syncthreads();
    if ((threadIdx.x & 63) == 0) redf[threadIdx.x >> 6] = v;
    __syncthreads();
    return fmaxf(fmaxf(redf[0], redf[1]), fmaxf(redf[2], redf[3]));
}
__device__ __forceinline__ float block_sum256(float v, float* redf) {
    #pragma unroll
    for (int off = 32; off; off >>= 1) v += __shfl_down(v, off);
    __syncthreads();
    if ((threadIdx.x & 63) == 0) redf[threadIdx.x >> 6] = v;
    __syncthreads();
    return (redf[0] + redf[1]) + (redf[2] + redf[3]);    // fixed order: deterministic
}

// ---- Kernel 3: per-row epilogue; launch_bounds(256,1) frees the VGPR budget ----
__global__ __launch_bounds__(256, 1) void k_epilogue(const float* __restrict__ x,
                                                  const float* __restrict__ W,
                                                  const int* __restrict__ radius_raw,
                                                  const float* __restrict__ gu,
                                                  const float* __restrict__ uvec,
                                                  const float* __restrict__ part,
                                                  const float* __restrict__ bias,
                                                  float* __restrict__ out,
                                                  int nsplit) {
    __shared__ float scx_s[Dd];        // 16 KB: sc values for flip-position lookups
    __shared__ float redf[2][4];       // double-buffered argmax combine
    __shared__ int   redi[2][4];
    __shared__ float redsum[4];
    __shared__ int   flips[MAXR];

    const int b = blockIdx.x;
    const int tid = threadIdx.x;
    const float* xrow  = x  + (size_t)b * Dd;
    const float* gurow = gu + (size_t)b * Dd;

    // ---- phase 1: grad = sum_z part[z] + bias (fixed order); sc/key in registers ----
    float4 g4[4], bs4[4], xv4[4], uu4[4];
    #pragma unroll
    for (int c = 0; c < 4; ++c) {
        int j = c * 1024 + tid * 4;
        g4[c]  = *(const float4*)(part + (size_t)b * Dd + j);      // z = 0
        bs4[c] = *(const float4*)(bias + j);
        xv4[c] = *(const float4*)(xrow + j);
        uu4[c] = *(const float4*)(gurow + j);
    }
    if (nsplit == 4) {
        // hand-unrolled: all 12 loads issue as one batch; add order ((p0+p1)+p2)+p3
        float4 p1[4], p2[4], p3[4];
        #pragma unroll
        for (int c = 0; c < 4; ++c) {
            int j = c * 1024 + tid * 4;
            p1[c] = *(const float4*)(part + (size_t)(1 * Bsz + b) * Dd + j);
            p2[c] = *(const float4*)(part + (size_t)(2 * Bsz + b) * Dd + j);
            p3[c] = *(const float4*)(part + (size_t)(3 * Bsz + b) * Dd + j);
        }
        #pragma unroll
        for (int c = 0; c < 4; ++c) {
            g4[c].x = ((g4[c].x + p1[c].x) + p2[c].x) + p3[c].x;
            g4[c].y = ((g4[c].y + p1[c].y) + p2[c].y) + p3[c].y;
            g4[c].z = ((g4[c].z + p1[c].z) + p2[c].z) + p3[c].z;
            g4[c].w = ((g4[c].w + p1[c].w) + p2[c].w) + p3[c].w;
        }
    } else {
        for (int z = 1; z < nsplit; ++z) {
            const float* pz = part + (size_t)z * (Bsz * Dd) + (size_t)b * Dd;
            #pragma unroll
            for (int c = 0; c < 4; ++c) {
                float4 a = *(const float4*)(pz + c * 1024 + tid * 4);
                g4[c].x += a.x; g4[c].y += a.y; g4[c].z += a.z; g4[c].w += a.w;
            }
        }
    }
    float sc[16], ky[16];
    float lmax = -FMAX;
    float lkey = -FMAX; int lidx = 0x7fffffff;
    #pragma unroll
    for (int c = 0; c < 4; ++c) {
        const float* gg = (const float*)&g4[c];
        const float* gc = (const float*)&bs4[c];
        const float* gx = (const float*)&xv4[c];
        const float* gup = (const float*)&uu4[c];
        #pragma unroll
        for (int e = 0; e < 4; ++e) {
            int r = c * 4 + e;
            float g = gg[e] + gc[e];
            float s = (1.0f - 2.0f * gx[e]) * g * 0.5f;
            float k = s - logf(-logf(fmaxf(gup[e], 1e-10f)));
            sc[r] = s;
            ky[r] = k;
            lmax = fmaxf(lmax, s);
            if (k > lkey) { lkey = k; lidx = c * 1024 + tid * 4 + e; }  // incr j: lowest-idx tie
        }
        *(float4*)&scx_s[c * 1024 + tid * 4] = *(const float4*)&sc[c * 4];
    }

    // ---- lse_x ----
    float mx = block_max256(lmax, redsum);
    float ls = 0.0f;
    #pragma unroll
    for (int r = 0; r < 16; ++r) ls += expf(sc[r] - mx);
    float sum_x = block_sum256(ls, redsum);
    float lse_x = mx + logf(sum_x);

    // ---- top-radius: tournament over register-cached per-thread maxima ----
    const int radius = radius_raw[b] + 1;             // [1, 15]
    unsigned removed = 0;
    for (int t = 0; t < radius; ++t) {
        float v = lkey; int idx = lidx;
        #pragma unroll
        for (int off = 32; off; off >>= 1) {
            float v2 = __shfl_down(v, off);
            int   i2 = __shfl_down(idx, off);
            if (v2 > v || (v2 == v && i2 < idx)) { v = v2; idx = i2; }
        }
        const int buf = t & 1;
        if ((tid & 63) == 0) { redf[buf][tid >> 6] = v; redi[buf][tid >> 6] = idx; }
        __syncthreads();
        float bv = redf[buf][0]; int bi = redi[buf][0];
        #pragma unroll
        for (int w2 = 1; w2 < 4; ++w2) {
            float v2 = redf[buf][w2]; int i2 = redi[buf][w2];
            if (v2 > bv || (v2 == bv && i2 < bi)) { bv = v2; bi = i2; }
        }
        if (tid == ((bi >> 2) & 255)) {       // owner: remove + rescan registers
            removed |= 1u << (((bi >> 10) << 2) | (bi & 3));
            lkey = -FMAX; lidx = 0x7fffffff;
            #pragma unroll
            for (int c = 0; c < 4; ++c)
                #pragma unroll
                for (int e = 0; e < 4; ++e) {
                    int r = c * 4 + e;
                    if (!(removed & (1u << r)) && ky[r] > lkey) {
                        lkey = ky[r]; lidx = c * 1024 + tid * 4 + e;
                    }
                }
        }
        if (tid == 0) flips[t] = bi;
    }
    __syncthreads();                           // flips[] visible to all

    // ---- lse_y via correction: sum_y = sum_x + sum_flips(e^{-sc-mx} - e^{+sc-mx}) ----
    float delta = 0.0f;
    if (tid < radius) {
        float sv = scx_s[flips[tid]];
        delta = expf(-sv - mx) - expf(sv - mx);
    }
    float sum_y = sum_x + block_sum256(delta, redsum);
    float lse_y = mx + logf(sum_y);

    // ---- pair term: 0.25 * sum_{p,q in flips} d_p d_q (W_pq + W_qp) ----
    float ts = 0.0f;
    for (int t = tid; t < radius * radius; t += 256) {
        int p = flips[t / radius], q = flips[t % radius];
        float dp = 1.0f - 2.0f * xrow[p];
        float dq = 1.0f - 2.0f * xrow[q];
        ts += 0.25f * dp * dq * (W[(size_t)p * Dd + q] + W[(size_t)q * Dd + p]);
    }
    float T = block_sum256(ts, redsum);

    float log_acc = fminf(T + lse_x - lse_y, 0.0f);
    int accepted = (expf(log_acc) > uvec[b]) ? 1 : 0;

    // ---- output: x everywhere (from registers), flips overwritten iff accepted ----
    float* orow = out + (size_t)b * Dd;
    #pragma unroll
    for (int c = 0; c < 4; ++c)
        *(float4*)(orow + c * 1024 + tid * 4) = xv4[c];
    __syncthreads();
    if (accepted && tid < radius) {
        int p = flips[tid];
        orow[p] = 1.0f - xrow[p];
    }
}

extern "C" void kernel_launch(void* const* d_in, const int* in_sizes, int n_in,
                              void* d_out, int out_size, void* d_ws, size_t ws_size,
                              hipStream_t stream) {
    const float* x          = (const float*)d_in[0];
    const float* W          = (const float*)d_in[1];
    const float* bias       = (const float*)d_in[2];
    const int*   radius_raw = (const int*)d_in[3];
    const float* gu         = (const float*)d_in[4];
    const float* u          = (const float*)d_in[5];
    float* out = (float*)d_out;

    // ws: xb 2.1 MB | part nsplit*4.19 MB   (shi/slo eliminated by fused GEMM)
    unsigned short* xb  = (unsigned short*)d_ws;
    float*          prt = (float*)(xb + (size_t)Bsz * Dd);

    // nsplit=4 (champion K-partition preserved); ws_size constant across calls => graph-safe.
    const size_t fixed = (size_t)Bsz * Dd * 2;
    const int nsplit = (ws_size >= fixed + (size_t)4 * Bsz * Dd * 4) ? 4 : 2;
    const int kchunk = Dd / nsplit;

    k_xconv<<<Bsz, 256, 0, stream>>>(x, xb);
    k_gemm<<<dim3(64, 1, nsplit), 512, 0, stream>>>(xb, W, prt, kchunk);
    k_epilogue<<<Bsz, 256, 0, stream>>>(x, W, radius_raw, gu, u, prt, bias, out, nsplit);
}

// Round 3
// 168.233 us; speedup vs baseline: 1.0309x; 1.0309x over previous
//
#include <hip/hip_runtime.h>

#define Bsz 256
#define Dd  4096
#define MAXR 15
#define FMAX 3.402823466e+38f
#define BK 64
#define LSTRIDE 72              // 9 granules (odd): conflict-free phases, 16B-aligned rows
#define T1PAD 65                // odd float pad: transposed read/write worst-case 2-way (free)

typedef short bf16x8 __attribute__((ext_vector_type(8)));
typedef float f32x4  __attribute__((ext_vector_type(4)));

__device__ __forceinline__ unsigned short f2bf(float f) {
    unsigned int u = __float_as_uint(f);
    unsigned int r = (u + 0x7fffu + ((u >> 16) & 1u)) >> 16;   // RNE
    return (unsigned short)r;
}
__device__ __forceinline__ float bf2f(unsigned short h) {
    return __uint_as_float(((unsigned int)h) << 16);
}

// ---- Kernel 1 (tiny): x fp32 -> bf16 (same rounding as champion's fused conversion) ----
__global__ __launch_bounds__(256) void k_xconv(const float* __restrict__ x,
                                               unsigned short* __restrict__ xb) {
    const int b = blockIdx.x;
    const int tid = threadIdx.x;
    const float* xp = x + (size_t)b * Dd;
    unsigned short* xo = xb + (size_t)b * Dd;
    #pragma unroll
    for (int c = 0; c < 4; ++c) {
        int e = c * 1024 + tid * 4;
        float4 v = *(const float4*)(xp + e);
        unsigned short o4[4] = { f2bf(v.x), f2bf(v.y), f2bf(v.z), f2bf(v.w) };
        *(uint2*)(xo + e) = *(const uint2*)o4;
    }
}

// ---- Kernel 2 (v4, fused): part[z] = X @ S(K-chunk z), S = 0.5(W+W^T) built on the fly ----
// BM=128 x BN=64, 256 threads / 4 waves (2m x 2n), grid (64,2,nsplit) = 512 blocks
// => 2 blocks/CU: cross-block overlap hides barrier/convert latency (v3 had 1/CU, 80% idle).
// Per BK=64 step: stage As (from reg-prefetched xb) + T1[k][n] (fp32 k-panel);
// convert s = 0.5(W[n][k](regs) + T1 transposed) -> f2bf hi/lo -> Bh/Bl; MFMA from LDS only.
// T1PAD=65 (odd): transposed reads/writes max 2-way bank alias = free (m136).
// S values, MFMA order, part layout bit-identical to champion -> absmax 0.0.
__global__ __launch_bounds__(256, 2) void k_gemm(const unsigned short* __restrict__ xb,
                                              const float* __restrict__ W,
                                              float* __restrict__ part,
                                              int kchunk) {
    __shared__ __align__(16) unsigned short As[128 * LSTRIDE];   // 18 KB
    __shared__ __align__(16) unsigned short Bh[64 * LSTRIDE];    //  9 KB
    __shared__ __align__(16) unsigned short Bl[64 * LSTRIDE];    //  9 KB
    __shared__ float T1[64 * T1PAD];                             // 16.25 KB
    const int tid = threadIdx.x;
    const int n0 = blockIdx.x * 64;
    const int m0 = blockIdx.y * 128;
    const int kbase = blockIdx.z * kchunk;
    const int w = tid >> 6, lane = tid & 63;
    const int ln = lane & 15, quad = lane >> 4;
    const int wm = w >> 1, wn = w & 1;     // wave grid: 2 in M, 2 in N

    // As staging: 128 rows x 8 granules-of-8 = 1024 slots, 4/thread
    unsigned ga[4]; int la[4];
    #pragma unroll
    for (int j = 0; j < 4; ++j) {
        int s = tid + j * 256;
        int r = s >> 3, g = s & 7;
        ga[j] = (unsigned)((m0 + r) * Dd + kbase + g * 8);
        la[j] = r * LSTRIDE + g * 8;
    }

    // T1 staging / convert slot: row rS (0..63), 16-col segment cS
    const int rS = tid >> 2;               // 0..63
    const int cS = (tid & 3) * 16;         // 0,16,32,48
    const float* w1p = W + (size_t)(kbase + rS) * Dd + (n0 + cS);   // k-panel row (advance k0*Dd)
    const float* w2p = W + (size_t)(n0 + rS) * Dd + (kbase + cS);   // n-panel row (advance k0)

    f32x4 acc[4][2];
    #pragma unroll
    for (int mt = 0; mt < 4; ++mt)
        #pragma unroll
        for (int ct = 0; ct < 2; ++ct)
            #pragma unroll
            for (int rr = 0; rr < 4; ++rr) acc[mt][ct][rr] = 0.0f;

    // prologue: step-0 operands in registers
    bf16x8 va[4];
    float4 w1[4], w2[4];
    #pragma unroll
    for (int j = 0; j < 4; ++j) va[j] = *(const bf16x8*)(xb + ga[j]);
    #pragma unroll
    for (int j = 0; j < 4; ++j) w1[j] = *(const float4*)(w1p + j * 4);
    #pragma unroll
    for (int j = 0; j < 4; ++j) w2[j] = *(const float4*)(w2p + j * 4);

    for (int k0 = 0; k0 < kchunk; k0 += BK) {
        __syncthreads();   // prev MFMA done with As/Bh/Bl; prev convert done with T1
        // ---- stage: As from va, T1 (k-panel, scalar b32: 2-way max) from w1 ----
        #pragma unroll
        for (int j = 0; j < 4; ++j) *(bf16x8*)&As[la[j]] = va[j];
        #pragma unroll
        for (int j4 = 0; j4 < 4; ++j4) {
            const float* f = (const float*)&w1[j4];
            #pragma unroll
            for (int e = 0; e < 4; ++e)
                T1[rS * T1PAD + cS + j4 * 4 + e] = f[e];
        }
        // ---- prefetch next step into registers (in flight across convert+MFMA) ----
        int kn = k0 + BK;
        int ks = (kn < kchunk) ? kn : 0;
        #pragma unroll
        for (int j = 0; j < 4; ++j) va[j] = *(const bf16x8*)(xb + ga[j] + ks);
        #pragma unroll
        for (int j = 0; j < 4; ++j) w1[j] = *(const float4*)(w1p + (size_t)ks * Dd + j * 4);
        float4 nw2[4];
        #pragma unroll
        for (int j = 0; j < 4; ++j) nw2[j] = *(const float4*)(w2p + ks + j * 4);
        __syncthreads();   // T1 visible
        // ---- convert: s[n=rS][k=cS+jj] = 0.5*(W[n][k] + W[k][n]) -> Bh/Bl ----
        {
            unsigned short vh[16], vl[16];
            #pragma unroll
            for (int j4 = 0; j4 < 4; ++j4) {
                const float* f = (const float*)&w2[j4];
                #pragma unroll
                for (int e = 0; e < 4; ++e) {
                    int jj = j4 * 4 + e;
                    float s = 0.5f * (f[e] + T1[(cS + jj) * T1PAD + rS]);
                    vh[jj] = f2bf(s);
                    vl[jj] = f2bf(s - bf2f(vh[jj]));
                }
            }
            *(bf16x8*)&Bh[rS * LSTRIDE + cS]     = *(const bf16x8*)&vh[0];
            *(bf16x8*)&Bh[rS * LSTRIDE + cS + 8] = *(const bf16x8*)&vh[8];
            *(bf16x8*)&Bl[rS * LSTRIDE + cS]     = *(const bf16x8*)&vl[0];
            *(bf16x8*)&Bl[rS * LSTRIDE + cS + 8] = *(const bf16x8*)&vl[8];
        }
        __syncthreads();   // Bh/Bl visible
        // ---- MFMA: all operands from LDS ----
        #pragma unroll
        for (int kk = 0; kk < BK; kk += 32) {
            const int gr = (kk >> 3) + quad;
            bf16x8 a[4];
            #pragma unroll
            for (int mt = 0; mt < 4; ++mt)
                a[mt] = *(const bf16x8*)&As[(wm * 64 + mt * 16 + ln) * LSTRIDE + gr * 8];
            #pragma unroll
            for (int ct = 0; ct < 2; ++ct) {
                int rb = wn * 32 + ct * 16 + ln;
                bf16x8 bh = *(const bf16x8*)&Bh[rb * LSTRIDE + gr * 8];
                bf16x8 bl = *(const bf16x8*)&Bl[rb * LSTRIDE + gr * 8];
                #pragma unroll
                for (int mt = 0; mt < 4; ++mt) {
                    acc[mt][ct] = __builtin_amdgcn_mfma_f32_16x16x32_bf16(a[mt], bh, acc[mt][ct], 0, 0, 0);
                    acc[mt][ct] = __builtin_amdgcn_mfma_f32_16x16x32_bf16(a[mt], bl, acc[mt][ct], 0, 0, 0);
                }
            }
        }
        #pragma unroll
        for (int j = 0; j < 4; ++j) w2[j] = nw2[j];   // rotate
    }
    float* prow = part + (size_t)blockIdx.z * (Bsz * Dd);
    #pragma unroll
    for (int mt = 0; mt < 4; ++mt)
        #pragma unroll
        for (int ct = 0; ct < 2; ++ct)
            #pragma unroll
            for (int rr = 0; rr < 4; ++rr) {
                int m = m0 + wm * 64 + mt * 16 + quad * 4 + rr;
                int n = n0 + wn * 32 + ct * 16 + ln;
                prow[(size_t)m * Dd + n] = acc[mt][ct][rr];
            }
}

// ---------------- block reduction helpers (256 threads = 4 waves) ----------------
__device__ __forceinline__ float block_max256(float v, float* redf) {
    #pragma unroll
    for (int off = 32; off; off >>= 1) v = fmaxf(v, __shfl_down(v, off));
    __syncthreads();
    if ((threadIdx.x & 63) == 0) redf[threadIdx.x >> 6] = v;
    __syncthreads();
    return fmaxf(fmaxf(redf[0], redf[1]), fmaxf(redf[2], redf[3]));
}
__device__ __forceinline__ float block_sum256(float v, float* redf) {
    #pragma unroll
    for (int off = 32; off; off >>= 1) v += __shfl_down(v, off);
    __syncthreads();
    if ((threadIdx.x & 63) == 0) redf[threadIdx.x >> 6] = v;
    __syncthreads();
    return (redf[0] + redf[1]) + (redf[2] + redf[3]);    // fixed order: deterministic
}

// ---- Kernel 3: per-row epilogue; launch_bounds(256,1) frees the VGPR budget ----
__global__ __launch_bounds__(256, 1) void k_epilogue(const float* __restrict__ x,
                                                  const float* __restrict__ W,
                                                  const int* __restrict__ radius_raw,
                                                  const float* __restrict__ gu,
                                                  const float* __restrict__ uvec,
                                                  const float* __restrict__ part,
                                                  const float* __restrict__ bias,
                                                  float* __restrict__ out,
                                                  int nsplit) {
    __shared__ float scx_s[Dd];        // 16 KB: sc values for flip-position lookups
    __shared__ float redf[2][4];       // double-buffered argmax combine
    __shared__ int   redi[2][4];
    __shared__ float redsum[4];
    __shared__ int   flips[MAXR];

    const int b = blockIdx.x;
    const int tid = threadIdx.x;
    const float* xrow  = x  + (size_t)b * Dd;
    const float* gurow = gu + (size_t)b * Dd;

    // ---- phase 1: grad = sum_z part[z] + bias (fixed order); sc/key in registers ----
    float4 g4[4], bs4[4], xv4[4], uu4[4];
    #pragma unroll
    for (int c = 0; c < 4; ++c) {
        int j = c * 1024 + tid * 4;
        g4[c]  = *(const float4*)(part + (size_t)b * Dd + j);      // z = 0
        bs4[c] = *(const float4*)(bias + j);
        xv4[c] = *(const float4*)(xrow + j);
        uu4[c] = *(const float4*)(gurow + j);
    }
    if (nsplit == 4) {
        // hand-unrolled: all 12 loads issue as one batch; add order ((p0+p1)+p2)+p3
        float4 p1[4], p2[4], p3[4];
        #pragma unroll
        for (int c = 0; c < 4; ++c) {
            int j = c * 1024 + tid * 4;
            p1[c] = *(const float4*)(part + (size_t)(1 * Bsz + b) * Dd + j);
            p2[c] = *(const float4*)(part + (size_t)(2 * Bsz + b) * Dd + j);
            p3[c] = *(const float4*)(part + (size_t)(3 * Bsz + b) * Dd + j);
        }
        #pragma unroll
        for (int c = 0; c < 4; ++c) {
            g4[c].x = ((g4[c].x + p1[c].x) + p2[c].x) + p3[c].x;
            g4[c].y = ((g4[c].y + p1[c].y) + p2[c].y) + p3[c].y;
            g4[c].z = ((g4[c].z + p1[c].z) + p2[c].z) + p3[c].z;
            g4[c].w = ((g4[c].w + p1[c].w) + p2[c].w) + p3[c].w;
        }
    } else {
        for (int z = 1; z < nsplit; ++z) {
            const float* pz = part + (size_t)z * (Bsz * Dd) + (size_t)b * Dd;
            #pragma unroll
            for (int c = 0; c < 4; ++c) {
                float4 a = *(const float4*)(pz + c * 1024 + tid * 4);
                g4[c].x += a.x; g4[c].y += a.y; g4[c].z += a.z; g4[c].w += a.w;
            }
        }
    }
    float sc[16], ky[16];
    float lmax = -FMAX;
    float lkey = -FMAX; int lidx = 0x7fffffff;
    #pragma unroll
    for (int c = 0; c < 4; ++c) {
        const float* gg = (const float*)&g4[c];
        const float* gc = (const float*)&bs4[c];
        const float* gx = (const float*)&xv4[c];
        const float* gup = (const float*)&uu4[c];
        #pragma unroll
        for (int e = 0; e < 4; ++e) {
            int r = c * 4 + e;
            float g = gg[e] + gc[e];
            float s = (1.0f - 2.0f * gx[e]) * g * 0.5f;
            float k = s - logf(-logf(fmaxf(gup[e], 1e-10f)));
            sc[r] = s;
            ky[r] = k;
            lmax = fmaxf(lmax, s);
            if (k > lkey) { lkey = k; lidx = c * 1024 + tid * 4 + e; }  // incr j: lowest-idx tie
        }
        *(float4*)&scx_s[c * 1024 + tid * 4] = *(const float4*)&sc[c * 4];
    }

    // ---- lse_x ----
    float mx = block_max256(lmax, redsum);
    float ls = 0.0f;
    #pragma unroll
    for (int r = 0; r < 16; ++r) ls += expf(sc[r] - mx);
    float sum_x = block_sum256(ls, redsum);
    float lse_x = mx + logf(sum_x);

    // ---- top-radius: tournament over register-cached per-thread maxima ----
    const int radius = radius_raw[b] + 1;             // [1, 15]
    unsigned removed = 0;
    for (int t = 0; t < radius; ++t) {
        float v = lkey; int idx = lidx;
        #pragma unroll
        for (int off = 32; off; off >>= 1) {
            float v2 = __shfl_down(v, off);
            int   i2 = __shfl_down(idx, off);
            if (v2 > v || (v2 == v && i2 < idx)) { v = v2; idx = i2; }
        }
        const int buf = t & 1;
        if ((tid & 63) == 0) { redf[buf][tid >> 6] = v; redi[buf][tid >> 6] = idx; }
        __syncthreads();
        float bv = redf[buf][0]; int bi = redi[buf][0];
        #pragma unroll
        for (int w2 = 1; w2 < 4; ++w2) {
            float v2 = redf[buf][w2]; int i2 = redi[buf][w2];
            if (v2 > bv || (v2 == bv && i2 < bi)) { bv = v2; bi = i2; }
        }
        if (tid == ((bi >> 2) & 255)) {       // owner: remove + rescan registers
            removed |= 1u << (((bi >> 10) << 2) | (bi & 3));
            lkey = -FMAX; lidx = 0x7fffffff;
            #pragma unroll
            for (int c = 0; c < 4; ++c)
                #pragma unroll
                for (int e = 0; e < 4; ++e) {
                    int r = c * 4 + e;
                    if (!(removed & (1u << r)) && ky[r] > lkey) {
                        lkey = ky[r]; lidx = c * 1024 + tid * 4 + e;
                    }
                }
        }
        if (tid == 0) flips[t] = bi;
    }
    __syncthreads();                           // flips[] visible to all

    // ---- lse_y via correction: sum_y = sum_x + sum_flips(e^{-sc-mx} - e^{+sc-mx}) ----
    float delta = 0.0f;
    if (tid < radius) {
        float sv = scx_s[flips[tid]];
        delta = expf(-sv - mx) - expf(sv - mx);
    }
    float sum_y = sum_x + block_sum256(delta, redsum);
    float lse_y = mx + logf(sum_y);

    // ---- pair term: 0.25 * sum_{p,q in flips} d_p d_q (W_pq + W_qp) ----
    float ts = 0.0f;
    for (int t = tid; t < radius * radius; t += 256) {
        int p = flips[t / radius], q = flips[t % radius];
        float dp = 1.0f - 2.0f * xrow[p];
        float dq = 1.0f - 2.0f * xrow[q];
        ts += 0.25f * dp * dq * (W[(size_t)p * Dd + q] + W[(size_t)q * Dd + p]);
    }
    float T = block_sum256(ts, redsum);

    float log_acc = fminf(T + lse_x - lse_y, 0.0f);
    int accepted = (expf(log_acc) > uvec[b]) ? 1 : 0;

    // ---- output: x everywhere (from registers), flips overwritten iff accepted ----
    float* orow = out + (size_t)b * Dd;
    #pragma unroll
    for (int c = 0; c < 4; ++c)
        *(float4*)(orow + c * 1024 + tid * 4) = xv4[c];
    __syncthreads();
    if (accepted && tid < radius) {
        int p = flips[tid];
        orow[p] = 1.0f - xrow[p];
    }
}

extern "C" void kernel_launch(void* const* d_in, const int* in_sizes, int n_in,
                              void* d_out, int out_size, void* d_ws, size_t ws_size,
                              hipStream_t stream) {
    const float* x          = (const float*)d_in[0];
    const float* W          = (const float*)d_in[1];
    const float* bias       = (const float*)d_in[2];
    const int*   radius_raw = (const int*)d_in[3];
    const float* gu         = (const float*)d_in[4];
    const float* u          = (const float*)d_in[5];
    float* out = (float*)d_out;

    // ws: xb 2.1 MB | part nsplit*4.19 MB   (shi/slo eliminated by fused GEMM)
    unsigned short* xb  = (unsigned short*)d_ws;
    float*          prt = (float*)(xb + (size_t)Bsz * Dd);

    // nsplit=4 (champion K-partition preserved); ws_size constant across calls => graph-safe.
    const size_t fixed = (size_t)Bsz * Dd * 2;
    const int nsplit = (ws_size >= fixed + (size_t)4 * Bsz * Dd * 4) ? 4 : 2;
    const int kchunk = Dd / nsplit;

    k_xconv<<<Bsz, 256, 0, stream>>>(x, xb);
    k_gemm<<<dim3(64, 2, nsplit), 256, 0, stream>>>(xb, W, prt, kchunk);
    k_epilogue<<<Bsz, 256, 0, stream>>>(x, W, radius_raw, gu, u, prt, bias, out, nsplit);
}